// Round 12
// baseline (588.466 us; speedup 1.0000x reference)
//
#include <hip/hip_runtime.h>
#include <hip/hip_bf16.h>

// ---------------------------------------------------------------------------
// GAT link-prediction forward: 3 GATConv layers on a fixed graph.
// R1: hierarchical scan.  R2: register-tiled f32 GEMM.
// R4/R10: XCD-partitioned single-atomic-pass CSR build.
// R5/R6/R8: gather pinned at ~3.65TB/s beyond-L2 service across 4 shapes.
// R7: fused softmax+gather.  R9 FAILED: bf16 messages (error amplification).
// R11: src-class-sorted CSR: only ~5% FETCH drop (resident waves are
//     uniformly phase-staggered -> window still spans S). Kept (free).
// R12: CSR build de-amplified: ushort2 edges (N<65536), one partition pass
//     (EI read once, LDS-staged 8-way dst-class split) -> rank/place read
//     only their bucket once. Build traffic ~317MB -> ~64MB. csr is ushort.
// ---------------------------------------------------------------------------

#define SCAN_BLOCK 256
#define KSHIFT 12                 // src-class width 4096 rows (2MB of S)
#define KC 13                     // ceil(50000/4096)

// Detect whether edge_index arrived as int64 (high words all zero) or int32.
__global__ void detect_i64(const unsigned* __restrict__ ei, int* __restrict__ flag) {
    if (threadIdx.x == 0 && blockIdx.x == 0) {
        int allz = 1;
        for (int i = 0; i < 128; ++i)
            if (ei[2 * i + 1] != 0u) { allz = 0; break; }
        *flag = allz;
    }
}

// Partition pass: read EI once (+self loops), split into 8 dst-class buckets
// of packed ushort2 (src | dst<<16). LDS staging: 1 LDS atomic per edge,
// 8 global atomics per block per iteration.
__global__ __launch_bounds__(256) void gat_partition(
    const void* __restrict__ ei, const int* __restrict__ flag, int nE, int nN,
    unsigned* __restrict__ bucket, int cap, int* __restrict__ gcnt) {
    __shared__ int lcnt[8];
    __shared__ int lbase[8];
    const int i64 = *flag;
    const int cw = (nN + 7) >> 3;
    const int tid = threadIdx.x;
    const long long total = (long long)nE + nN;
    const long long stride = (long long)gridDim.x * blockDim.x;
    for (long long i = (long long)blockIdx.x * blockDim.x + tid; ; i += stride) {
        // does any thread in this block still have work this iteration?
        const long long iter_base = i - tid;
        if (iter_base >= total) break;
        if (tid < 8) lcnt[tid] = 0;
        __syncthreads();
        const bool has = i < total;
        int s = 0, d = 0, cls = 0, lpos = 0;
        if (has) {
            if (i < nE) {
                if (i64) { s = (int)((const long long*)ei)[i]; d = (int)((const long long*)ei)[nE + i]; }
                else     { s = ((const int*)ei)[i];            d = ((const int*)ei)[nE + i]; }
            } else { s = d = (int)(i - nE); }
            cls = d / cw;
            lpos = atomicAdd(&lcnt[cls], 1);
        }
        __syncthreads();
        if (tid < 8 && lcnt[tid] > 0) lbase[tid] = atomicAdd(&gcnt[tid], lcnt[tid]);
        __syncthreads();
        if (has) {
            const int pos = lbase[cls] + lpos;
            if (pos < cap) bucket[(size_t)cls * cap + pos] = (unsigned)s | ((unsigned)d << 16);
        }
        __syncthreads();
    }
}

// Rank pass: blocks of class c=blockIdx&7 read ONLY bucket c (once,
// coalesced). cnt2 atomics are XCD-local (all dsts in class c). rank[]
// indexed by bucket slot, written coalesced.
__global__ __launch_bounds__(256) void gat_rankb(
    const unsigned* __restrict__ bucket, const int* __restrict__ gcnt, int cap,
    int* __restrict__ cnt2, int* __restrict__ rank) {
    const int c = blockIdx.x & 7;
    const int m = gcnt[c];
    const unsigned* bk = bucket + (size_t)c * cap;
    int* rk = rank + (size_t)c * cap;
    const int stride = (gridDim.x >> 3) * blockDim.x;
    for (int j = (blockIdx.x >> 3) * blockDim.x + threadIdx.x; j < m; j += stride) {
        const unsigned e = bk[j];
        const int s = e & 0xFFFF, d = e >> 16;
        const int bin = d * KC + (s >> KSHIFT);
        rk[j] = atomicAdd(&cnt2[bin], 1);
    }
}

// Stage 1: per-block (256-element) inclusive scan + block totals. (generic)
__global__ __launch_bounds__(SCAN_BLOCK) void scan_stage1(
    const int* __restrict__ cnt, int* __restrict__ partial, int* __restrict__ bsum, int n) {
    __shared__ int tmp[SCAN_BLOCK];
    const int i = blockIdx.x * SCAN_BLOCK + threadIdx.x;
    const int v = (i < n) ? cnt[i] : 0;
    tmp[threadIdx.x] = v;
    __syncthreads();
    #pragma unroll
    for (int off = 1; off < SCAN_BLOCK; off <<= 1) {
        const int t = (threadIdx.x >= off) ? tmp[threadIdx.x - off] : 0;
        __syncthreads();
        tmp[threadIdx.x] += t;
        __syncthreads();
    }
    if (i < n) partial[i] = tmp[threadIdx.x];
    if (threadIdx.x == SCAN_BLOCK - 1) bsum[blockIdx.x] = tmp[threadIdx.x];
}

// Stage 2: one wave exclusive-scans nb (small) sums in place; total->rowp[n].
__global__ void scan_stage2(int* __restrict__ bsum, int nb, int* __restrict__ rowp, int n) {
    const int lane = threadIdx.x;  // blockDim = 64, grid = 1
    int carry = 0;
    for (int base = 0; base < nb; base += 64) {
        const int i = base + lane;
        const int v = (i < nb) ? bsum[i] : 0;
        int incl = v;
        #pragma unroll
        for (int off = 1; off < 64; off <<= 1) {
            const int t = __shfl_up(incl, off);
            if (lane >= off) incl += t;
        }
        if (i < nb) bsum[i] = carry + incl - v;  // exclusive
        carry += __shfl(incl, 63);
    }
    if (lane == 0) rowp[n] = carry;
}

// Stage 3 (3-level combine): rowp[i] = bsumBex[i>>16] + (partB-bsumA)[i>>8]
//                                     + (part2-cnt2)[i].
__global__ __launch_bounds__(SCAN_BLOCK) void scan_stage3v2(
    const int* __restrict__ part2, const int* __restrict__ cnt2,
    const int* __restrict__ bsumA, const int* __restrict__ partB,
    const int* __restrict__ bsumB, int* __restrict__ rowp, int n) {
    const int i = blockIdx.x * SCAN_BLOCK + threadIdx.x;
    if (i < n) {
        const int b1 = i >> 8;
        rowp[i] = bsumB[b1 >> 8] + (partB[b1] - bsumA[b1]) + (part2[i] - cnt2[i]);
    }
}

// Place pass: atomic-free; reads only bucket c + its rank slice (once),
// writes csr (ushort) at rowp2[bin]+rank — class-local contiguous regions.
__global__ __launch_bounds__(256) void gat_placeb(
    const unsigned* __restrict__ bucket, const int* __restrict__ gcnt, int cap,
    const int* __restrict__ rank, const int* __restrict__ rowp2,
    unsigned short* __restrict__ csr) {
    const int c = blockIdx.x & 7;
    const int m = gcnt[c];
    const unsigned* bk = bucket + (size_t)c * cap;
    const int* rk = rank + (size_t)c * cap;
    const int stride = (gridDim.x >> 3) * blockDim.x;
    for (int j = (blockIdx.x >> 3) * blockDim.x + threadIdx.x; j < m; j += stride) {
        const unsigned e = bk[j];
        const int s = e & 0xFFFF, d = e >> 16;
        const int bin = d * KC + (s >> KSHIFT);
        csr[rowp2[bin] + rk[j]] = (unsigned short)s;
    }
}

// S = Xin @ W (50000x128 @ 128x128 f32), register-tiled.
__global__ __launch_bounds__(256) void gemm_alpha(
    const float* __restrict__ Xin, const float* __restrict__ W,
    const float* __restrict__ avs, const float* __restrict__ avd,
    float* __restrict__ S, float* __restrict__ as_, float* __restrict__ ad_, int n) {
    __shared__ float Xl[64][128];
    const int tid = threadIdx.x;
    const int row0 = blockIdx.x * 64;
    for (int i = tid; i < 64 * 32; i += 256) {
        const int r = i >> 5, c4 = i & 31;
        const int gr = row0 + r;
        float4 v = (gr < n) ? ((const float4*)(Xin + (size_t)gr * 128))[c4]
                            : make_float4(0.f, 0.f, 0.f, 0.f);
        ((float4*)(&Xl[r][0]))[c4] = v;
    }
    __syncthreads();
    const int col4 = tid & 31;   // cols 4*col4 .. +3 (head = col4>>4)
    const int rowg = tid >> 5;   // rows 8*rowg .. +7
    float4 acc[8];
    #pragma unroll
    for (int r = 0; r < 8; ++r) acc[r] = make_float4(0.f, 0.f, 0.f, 0.f);
    const float* Wc = W + col4 * 4;
    for (int kk = 0; kk < 128; kk += 4) {
        const float4 w0 = *(const float4*)(Wc + (size_t)(kk + 0) * 128);
        const float4 w1 = *(const float4*)(Wc + (size_t)(kk + 1) * 128);
        const float4 w2 = *(const float4*)(Wc + (size_t)(kk + 2) * 128);
        const float4 w3 = *(const float4*)(Wc + (size_t)(kk + 3) * 128);
        #pragma unroll
        for (int r = 0; r < 8; ++r) {
            const float4 x = *(const float4*)(&Xl[rowg * 8 + r][kk]);
            acc[r].x = fmaf(x.x, w0.x, acc[r].x); acc[r].y = fmaf(x.x, w0.y, acc[r].y);
            acc[r].z = fmaf(x.x, w0.z, acc[r].z); acc[r].w = fmaf(x.x, w0.w, acc[r].w);
            acc[r].x = fmaf(x.y, w1.x, acc[r].x); acc[r].y = fmaf(x.y, w1.y, acc[r].y);
            acc[r].z = fmaf(x.y, w1.z, acc[r].z); acc[r].w = fmaf(x.y, w1.w, acc[r].w);
            acc[r].x = fmaf(x.z, w2.x, acc[r].x); acc[r].y = fmaf(x.z, w2.y, acc[r].y);
            acc[r].z = fmaf(x.z, w2.z, acc[r].z); acc[r].w = fmaf(x.z, w2.w, acc[r].w);
            acc[r].x = fmaf(x.w, w3.x, acc[r].x); acc[r].y = fmaf(x.w, w3.y, acc[r].y);
            acc[r].z = fmaf(x.w, w3.z, acc[r].z); acc[r].w = fmaf(x.w, w3.w, acc[r].w);
        }
    }
    const float4 av = ((const float4*)avs)[col4];
    const float4 dv = ((const float4*)avd)[col4];
    #pragma unroll
    for (int r = 0; r < 8; ++r) {
        const int grow = row0 + rowg * 8 + r;
        if (grow < n) ((float4*)(S + (size_t)grow * 128))[col4] = acc[r];
        float ps = acc[r].x * av.x + acc[r].y * av.y + acc[r].z * av.z + acc[r].w * av.w;
        float pd = acc[r].x * dv.x + acc[r].y * dv.y + acc[r].z * dv.z + acc[r].w * dv.w;
        #pragma unroll
        for (int off = 8; off; off >>= 1) {  // reduce 16 col-lanes of this head
            ps += __shfl_xor(ps, off);
            pd += __shfl_xor(pd, off);
        }
        if ((col4 & 15) == 0 && grow < n) {
            const int h = col4 >> 4;
            as_[2 * grow + h] = ps;
            ad_[2 * grow + h] = pd;
        }
    }
}

// Fused softmax + gather: one wave per dst; edges of dst d occupy
// [rowp2[d*KC], rowp2[(d+1)*KC]) in ascending src-class order. csr is ushort.
// Fast path (deg<=64): stats in registers, alpha via __shfl. 16-lane edge
// groups: 4 edges concurrent; invalid tail groups skip their loads.
// mode 0=ELU(concat), 1=ReLU(concat), 2=ReLU(head-mean).
__global__ __launch_bounds__(256) void gat_fused(
    const float* __restrict__ S, const float* __restrict__ as_,
    const float* __restrict__ ad_, const int* __restrict__ rowp2,
    const unsigned short* __restrict__ csr, const float* __restrict__ bias,
    float* __restrict__ out, int n, int mode) {
    const int lane = threadIdx.x & 63;
    const int d = (blockIdx.x * blockDim.x + threadIdx.x) >> 6;
    if (d >= n) return;
    const int beg = rowp2[d * KC], end = rowp2[(d + 1) * KC];
    const int deg = end - beg;
    const float2 adv = *(const float2*)(ad_ + 2 * d);
    const int g = lane >> 4;    // edge group 0..3
    const int gl = lane & 15;   // float4 col: gl (head0), 16+gl (head1)
    float4 acc0 = make_float4(0.f, 0.f, 0.f, 0.f);
    float4 acc1 = make_float4(0.f, 0.f, 0.f, 0.f);
    if (deg <= 64) {
        // ---- stats in registers ----
        const bool has = lane < deg;
        const int s_reg = has ? (int)csr[beg + lane] : 0;
        float e0 = -1e30f, e1 = -1e30f;
        if (has) {
            const float2 asv = *(const float2*)(as_ + 2 * s_reg);
            e0 = asv.x + adv.x; e0 = e0 > 0.f ? e0 : 0.2f * e0;
            e1 = asv.y + adv.y; e1 = e1 > 0.f ? e1 : 0.2f * e1;
        }
        float m0 = e0, m1 = e1;
        #pragma unroll
        for (int off = 32; off; off >>= 1) {
            m0 = fmaxf(m0, __shfl_xor(m0, off));
            m1 = fmaxf(m1, __shfl_xor(m1, off));
        }
        const float p0 = has ? __expf(e0 - m0) : 0.f;
        const float p1 = has ? __expf(e1 - m1) : 0.f;
        float s0 = p0, s1 = p1;
        #pragma unroll
        for (int off = 32; off; off >>= 1) {
            s0 += __shfl_xor(s0, off);
            s1 += __shfl_xor(s1, off);
        }
        const float inv0 = 1.f / s0, inv1 = 1.f / s1;
        // ---- gather; alpha via shfl; edges in src-ascending order ----
        int k = 0;
        for (; k + 4 <= deg; k += 4) {
            const int ke = k + g;
            const int sv = __shfl(s_reg, ke);
            const float a0 = __shfl(p0, ke) * inv0;
            const float a1 = __shfl(p1, ke) * inv1;
            const float4* r = (const float4*)(S + ((size_t)sv << 7));
            const float4 v0 = r[gl], v1 = r[16 + gl];
            acc0.x = fmaf(a0, v0.x, acc0.x); acc0.y = fmaf(a0, v0.y, acc0.y);
            acc0.z = fmaf(a0, v0.z, acc0.z); acc0.w = fmaf(a0, v0.w, acc0.w);
            acc1.x = fmaf(a1, v1.x, acc1.x); acc1.y = fmaf(a1, v1.y, acc1.y);
            acc1.z = fmaf(a1, v1.z, acc1.z); acc1.w = fmaf(a1, v1.w, acc1.w);
        }
        if (k < deg) {
            const int ke = k + g;
            const bool valid = ke < deg;
            const int idx = valid ? ke : 0;
            const int sv = __shfl(s_reg, idx);
            const float q0 = __shfl(p0, idx), q1 = __shfl(p1, idx);
            if (valid) {  // invalid groups skip the load entirely
                const float a0 = q0 * inv0, a1 = q1 * inv1;
                const float4* r = (const float4*)(S + ((size_t)sv << 7));
                const float4 v0 = r[gl], v1 = r[16 + gl];
                acc0.x = fmaf(a0, v0.x, acc0.x); acc0.y = fmaf(a0, v0.y, acc0.y);
                acc0.z = fmaf(a0, v0.z, acc0.z); acc0.w = fmaf(a0, v0.w, acc0.w);
                acc1.x = fmaf(a1, v1.x, acc1.x); acc1.y = fmaf(a1, v1.y, acc1.y);
                acc1.z = fmaf(a1, v1.z, acc1.z); acc1.w = fmaf(a1, v1.w, acc1.w);
            }
        }
    } else {
        // ---- slow path (deg>64, rare) ----
        float m0 = -1e30f, m1 = -1e30f;
        for (int i = beg + lane; i < end; i += 64) {
            const int s = (int)csr[i];
            const float2 asv = *(const float2*)(as_ + 2 * s);
            float e0 = asv.x + adv.x; e0 = e0 > 0.f ? e0 : 0.2f * e0;
            float e1 = asv.y + adv.y; e1 = e1 > 0.f ? e1 : 0.2f * e1;
            m0 = fmaxf(m0, e0); m1 = fmaxf(m1, e1);
        }
        #pragma unroll
        for (int off = 32; off; off >>= 1) {
            m0 = fmaxf(m0, __shfl_xor(m0, off));
            m1 = fmaxf(m1, __shfl_xor(m1, off));
        }
        float s0 = 0.f, s1 = 0.f;
        for (int i = beg + lane; i < end; i += 64) {
            const int s = (int)csr[i];
            const float2 asv = *(const float2*)(as_ + 2 * s);
            float e0 = asv.x + adv.x; e0 = e0 > 0.f ? e0 : 0.2f * e0;
            float e1 = asv.y + adv.y; e1 = e1 > 0.f ? e1 : 0.2f * e1;
            s0 += __expf(e0 - m0); s1 += __expf(e1 - m1);
        }
        #pragma unroll
        for (int off = 32; off; off >>= 1) {
            s0 += __shfl_xor(s0, off);
            s1 += __shfl_xor(s1, off);
        }
        const float inv0 = 1.f / s0, inv1 = 1.f / s1;
        for (int k = 0; k < deg; k += 4) {
            const int ke = k + g;
            if (ke < deg) {
                const int sv = (int)csr[beg + ke];
                const float2 asv = *(const float2*)(as_ + 2 * sv);
                float e0 = asv.x + adv.x; e0 = e0 > 0.f ? e0 : 0.2f * e0;
                float e1 = asv.y + adv.y; e1 = e1 > 0.f ? e1 : 0.2f * e1;
                const float a0 = __expf(e0 - m0) * inv0;
                const float a1 = __expf(e1 - m1) * inv1;
                const float4* r = (const float4*)(S + ((size_t)sv << 7));
                const float4 v0 = r[gl], v1 = r[16 + gl];
                acc0.x = fmaf(a0, v0.x, acc0.x); acc0.y = fmaf(a0, v0.y, acc0.y);
                acc0.z = fmaf(a0, v0.z, acc0.z); acc0.w = fmaf(a0, v0.w, acc0.w);
                acc1.x = fmaf(a1, v1.x, acc1.x); acc1.y = fmaf(a1, v1.y, acc1.y);
                acc1.z = fmaf(a1, v1.z, acc1.z); acc1.w = fmaf(a1, v1.w, acc1.w);
            }
        }
    }
    // reduce across the 4 edge groups (lane l, l^16, l^32, l^48 same cols)
    #pragma unroll
    for (int off = 16; off <= 32; off <<= 1) {
        acc0.x += __shfl_xor(acc0.x, off); acc0.y += __shfl_xor(acc0.y, off);
        acc0.z += __shfl_xor(acc0.z, off); acc0.w += __shfl_xor(acc0.w, off);
        acc1.x += __shfl_xor(acc1.x, off); acc1.y += __shfl_xor(acc1.y, off);
        acc1.z += __shfl_xor(acc1.z, off); acc1.w += __shfl_xor(acc1.w, off);
    }
    if (mode == 2) {
        if (lane < 16) {
            const float4 b = ((const float4*)bias)[gl];
            float4 o;
            o.x = fmaxf(0.5f * (acc0.x + acc1.x) + b.x, 0.f);
            o.y = fmaxf(0.5f * (acc0.y + acc1.y) + b.y, 0.f);
            o.z = fmaxf(0.5f * (acc0.z + acc1.z) + b.z, 0.f);
            o.w = fmaxf(0.5f * (acc0.w + acc1.w) + b.w, 0.f);
            ((float4*)(out + (size_t)d * 64))[gl] = o;
        }
    } else if (lane < 32) {
        const int ci = (lane < 16) ? gl : 16 + gl;   // float4 col index
        const float4 a = (lane < 16) ? acc0 : acc1;
        const float4 b = ((const float4*)bias)[ci];
        float4 o;
        o.x = a.x + b.x; o.y = a.y + b.y; o.z = a.z + b.z; o.w = a.w + b.w;
        if (mode == 0) {
            o.x = o.x > 0.f ? o.x : expm1f(o.x);
            o.y = o.y > 0.f ? o.y : expm1f(o.y);
            o.z = o.z > 0.f ? o.z : expm1f(o.z);
            o.w = o.w > 0.f ? o.w : expm1f(o.w);
        } else {
            o.x = fmaxf(o.x, 0.f); o.y = fmaxf(o.y, 0.f);
            o.z = fmaxf(o.z, 0.f); o.w = fmaxf(o.w, 0.f);
        }
        ((float4*)(out + (size_t)d * 128))[ci] = o;
    }
}

extern "C" void kernel_launch(void* const* d_in, const int* in_sizes, int n_in,
                              void* d_out, int out_size, void* d_ws, size_t ws_size,
                              hipStream_t stream) {
    const float* X   = (const float*)d_in[0];
    const void*  EI  = d_in[1];
    const float* W0  = (const float*)d_in[2];
    const float* as0 = (const float*)d_in[3];
    const float* ad0 = (const float*)d_in[4];
    const float* b0  = (const float*)d_in[5];
    const float* W1  = (const float*)d_in[6];
    const float* as1 = (const float*)d_in[7];
    const float* ad1 = (const float*)d_in[8];
    const float* b1  = (const float*)d_in[9];
    const float* W2  = (const float*)d_in[10];
    const float* as2 = (const float*)d_in[11];
    const float* ad2 = (const float*)d_in[12];
    const float* b2  = (const float*)d_in[13];

    const int N  = in_sizes[0] / 128;   // 50000
    const int E  = in_sizes[1] / 2;     // 1600000
    const int ET = E + N;               // + self loops
    const int NBINS = N * KC;           // 650000
    const int NB2 = (NBINS + SCAN_BLOCK - 1) / SCAN_BLOCK;  // 2540
    const int NB3 = (NB2 + SCAN_BLOCK - 1) / SCAN_BLOCK;    // 10
    // bucket capacity per dst-class: ~ET/8 * 1.25, rounded up
    const int cap = ((ET / 8) * 5 / 4 + 255) & ~255;

    char* p = (char*)d_ws;
    size_t used = 0;
    auto alloc = [&](size_t bytes) -> void* {
        void* r = p + used;
        used += (bytes + 255) & ~(size_t)255;
        return r;
    };
    float*          S     = (float*)alloc((size_t)N * 128 * 4);
    float*          H0    = (float*)alloc((size_t)N * 128 * 4);
    float*          H1    = (float*)alloc((size_t)N * 128 * 4);
    unsigned short* csr   = (unsigned short*)alloc((size_t)ET * 2);
    int*            rowp2 = (int*)alloc((size_t)(NBINS + 1) * 4);
    int*            cnt2  = (int*)alloc((size_t)NBINS * 4);
    int*            part2 = (int*)alloc((size_t)NBINS * 4);
    int*            bsumA = (int*)alloc((size_t)NB2 * 4);
    int*            partB = (int*)alloc((size_t)NB2 * 4);
    int*            bsumB = (int*)alloc((size_t)NB3 * 4);
    float*          asb   = (float*)alloc((size_t)N * 2 * 4);
    float*          adb   = (float*)alloc((size_t)N * 2 * 4);
    int*            flag  = (int*)alloc(256);
    int*            gcnt  = (int*)alloc(256);
    if (used > ws_size) return;  // fail loudly (validation will catch)
    // bucket (8*cap*4B ~ 8.3MB) + rank (8.3MB) alias S (25.6MB): both dead
    // before gemm0 writes S.
    unsigned* bucket = (unsigned*)S;
    int*      rank   = (int*)(bucket + (size_t)8 * cap);

    hipMemsetAsync(cnt2, 0, (size_t)NBINS * 4, stream);
    hipMemsetAsync(gcnt, 0, 256, stream);
    detect_i64<<<1, 64, 0, stream>>>((const unsigned*)EI, flag);
    gat_partition<<<2048, 256, 0, stream>>>(EI, flag, E, N, bucket, cap, gcnt);
    gat_rankb<<<2048, 256, 0, stream>>>(bucket, gcnt, cap, cnt2, rank);
    scan_stage1<<<NB2, SCAN_BLOCK, 0, stream>>>(cnt2, part2, bsumA, NBINS);
    scan_stage1<<<NB3, SCAN_BLOCK, 0, stream>>>(bsumA, partB, bsumB, NB2);
    scan_stage2<<<1, 64, 0, stream>>>(bsumB, NB3, rowp2, NBINS);
    scan_stage3v2<<<NB2, SCAN_BLOCK, 0, stream>>>(part2, cnt2, bsumA, partB, bsumB, rowp2, NBINS);
    gat_placeb<<<2048, 256, 0, stream>>>(bucket, gcnt, cap, rank, rowp2, csr);

    const int gemm_blocks = (N + 63) / 64;
    const int wave_blocks = (N + 3) / 4;  // 4 waves/block, 1 dst/wave

    // layer 0: GATConv(128 -> 64, H=2, concat) + ELU
    gemm_alpha<<<gemm_blocks, 256, 0, stream>>>(X, W0, as0, ad0, S, asb, adb, N);
    gat_fused<<<wave_blocks, 256, 0, stream>>>(S, asb, adb, rowp2, csr, b0, H0, N, 0);
    // layer 1: GATConv(128 -> 64, H=2, concat) + ReLU
    gemm_alpha<<<gemm_blocks, 256, 0, stream>>>(H0, W1, as1, ad1, S, asb, adb, N);
    gat_fused<<<wave_blocks, 256, 0, stream>>>(S, asb, adb, rowp2, csr, b1, H1, N, 1);
    // layer 2: GATConvMean(128 -> 64, H=2, mean) + ReLU
    gemm_alpha<<<gemm_blocks, 256, 0, stream>>>(H1, W2, as2, ad2, S, asb, adb, N);
    gat_fused<<<wave_blocks, 256, 0, stream>>>(S, asb, adb, rowp2, csr, b2, (float*)d_out, N, 2);
}

// Round 13
// 517.055 us; speedup vs baseline: 1.1381x; 1.1381x over previous
//
#include <hip/hip_runtime.h>
#include <hip/hip_bf16.h>

// ---------------------------------------------------------------------------
// GAT link-prediction forward: 3 GATConv layers on a fixed graph.
// R1: hierarchical scan.  R2: register-tiled f32 GEMM.
// R4/R10: XCD-partitioned single-atomic-pass CSR build.
// R5/R6/R8: gather pinned at ~3.7TB/s beyond-L2 service across 4 shapes.
// R7: fused softmax+gather.  R9 FAILED: bf16 messages (error amplification).
// R11: src-class-sorted CSR (kept; ~5% FETCH gain).
// R12 REGRESSED: LDS-partition build added a cross-XCD gcnt hot-line
//     (+60us). Reverted to R11 build structure.
// R13: same build, fewer bytes: packed u32 edges (s|d<<16), ushort rank,
//     ushort csr (kept from R12, -3us/fused). Build traffic ~300->~150MB.
// ---------------------------------------------------------------------------

#define SCAN_BLOCK 256
#define KSHIFT 12                 // src-class width 4096 rows (2MB of S)
#define KC 13                     // ceil(50000/4096)

// Detect whether edge_index arrived as int64 (high words all zero) or int32.
__global__ void detect_i64(const unsigned* __restrict__ ei, int* __restrict__ flag) {
    if (threadIdx.x == 0 && blockIdx.x == 0) {
        int allz = 1;
        for (int i = 0; i < 128; ++i)
            if (ei[2 * i + 1] != 0u) { allz = 0; break; }
        *flag = allz;
    }
}

// Streaming conversion: edge list (+implicit self loops) -> packed u32
// (src | dst<<16), both < 65536.
__global__ __launch_bounds__(256) void gat_convert(
    const void* __restrict__ ei, const int* __restrict__ flag, int nE, int nN,
    unsigned* __restrict__ epack) {
    const int i64 = *flag;
    const long long total = (long long)nE + nN;
    const long long stride = (long long)gridDim.x * blockDim.x;
    for (long long i = (long long)blockIdx.x * blockDim.x + threadIdx.x; i < total; i += stride) {
        int s, d;
        if (i < nE) {
            if (i64) { s = (int)((const long long*)ei)[i]; d = (int)((const long long*)ei)[nE + i]; }
            else     { s = ((const int*)ei)[i];            d = ((const int*)ei)[nE + i]; }
        } else { s = d = (int)(i - nE); }
        epack[i] = (unsigned)s | ((unsigned)d << 16);
    }
}

// Single atomic pass over (dst, srcclass) bins. Blocks of class c=blockIdx&7
// handle only dsts in [c*cw,(c+1)*cw) -> cnt2 atomics stay XCD-local.
// rank stored as ushort (bin counts << 65536).
__global__ __launch_bounds__(256) void gat_rankp(
    const unsigned* __restrict__ epack, long long total, int nN,
    int* __restrict__ cnt2, unsigned short* __restrict__ rank) {
    const int cw = (nN + 7) >> 3;
    const int lo = (blockIdx.x & 7) * cw;
    const long long stride = (long long)(gridDim.x >> 3) * blockDim.x;
    for (long long i = (long long)(blockIdx.x >> 3) * blockDim.x + threadIdx.x;
         i < total; i += stride) {
        const unsigned e = epack[i];
        const int s = (int)(e & 0xFFFFu), d = (int)(e >> 16);
        if ((unsigned)(d - lo) >= (unsigned)cw) continue;
        const int bin = d * KC + (s >> KSHIFT);
        rank[i] = (unsigned short)atomicAdd(&cnt2[bin], 1);
    }
}

// Stage 1: per-block (256-element) inclusive scan + block totals. (generic)
__global__ __launch_bounds__(SCAN_BLOCK) void scan_stage1(
    const int* __restrict__ cnt, int* __restrict__ partial, int* __restrict__ bsum, int n) {
    __shared__ int tmp[SCAN_BLOCK];
    const int i = blockIdx.x * SCAN_BLOCK + threadIdx.x;
    const int v = (i < n) ? cnt[i] : 0;
    tmp[threadIdx.x] = v;
    __syncthreads();
    #pragma unroll
    for (int off = 1; off < SCAN_BLOCK; off <<= 1) {
        const int t = (threadIdx.x >= off) ? tmp[threadIdx.x - off] : 0;
        __syncthreads();
        tmp[threadIdx.x] += t;
        __syncthreads();
    }
    if (i < n) partial[i] = tmp[threadIdx.x];
    if (threadIdx.x == SCAN_BLOCK - 1) bsum[blockIdx.x] = tmp[threadIdx.x];
}

// Stage 2: one wave exclusive-scans nb (small) sums in place; total->rowp[n].
__global__ void scan_stage2(int* __restrict__ bsum, int nb, int* __restrict__ rowp, int n) {
    const int lane = threadIdx.x;  // blockDim = 64, grid = 1
    int carry = 0;
    for (int base = 0; base < nb; base += 64) {
        const int i = base + lane;
        const int v = (i < nb) ? bsum[i] : 0;
        int incl = v;
        #pragma unroll
        for (int off = 1; off < 64; off <<= 1) {
            const int t = __shfl_up(incl, off);
            if (lane >= off) incl += t;
        }
        if (i < nb) bsum[i] = carry + incl - v;  // exclusive
        carry += __shfl(incl, 63);
    }
    if (lane == 0) rowp[n] = carry;
}

// Stage 3 (3-level combine): rowp[i] = bsumBex[i>>16] + (partB-bsumA)[i>>8]
//                                     + (part2-cnt2)[i].
__global__ __launch_bounds__(SCAN_BLOCK) void scan_stage3v2(
    const int* __restrict__ part2, const int* __restrict__ cnt2,
    const int* __restrict__ bsumA, const int* __restrict__ partB,
    const int* __restrict__ bsumB, int* __restrict__ rowp, int n) {
    const int i = blockIdx.x * SCAN_BLOCK + threadIdx.x;
    if (i < n) {
        const int b1 = i >> 8;
        rowp[i] = bsumB[b1 >> 8] + (partB[b1] - bsumA[b1]) + (part2[i] - cnt2[i]);
    }
}

// Atomic-free placement, same dst-class partition: each class writes its
// contiguous csr regions (ushort).
__global__ __launch_bounds__(256) void gat_placep(
    const unsigned* __restrict__ epack, const unsigned short* __restrict__ rank,
    const int* __restrict__ rowp2, long long total, int nN,
    unsigned short* __restrict__ csr) {
    const int cw = (nN + 7) >> 3;
    const int lo = (blockIdx.x & 7) * cw;
    const long long stride = (long long)(gridDim.x >> 3) * blockDim.x;
    for (long long i = (long long)(blockIdx.x >> 3) * blockDim.x + threadIdx.x;
         i < total; i += stride) {
        const unsigned e = epack[i];
        const int s = (int)(e & 0xFFFFu), d = (int)(e >> 16);
        if ((unsigned)(d - lo) >= (unsigned)cw) continue;
        const int bin = d * KC + (s >> KSHIFT);
        csr[rowp2[bin] + (int)rank[i]] = (unsigned short)s;
    }
}

// S = Xin @ W (50000x128 @ 128x128 f32), register-tiled.
__global__ __launch_bounds__(256) void gemm_alpha(
    const float* __restrict__ Xin, const float* __restrict__ W,
    const float* __restrict__ avs, const float* __restrict__ avd,
    float* __restrict__ S, float* __restrict__ as_, float* __restrict__ ad_, int n) {
    __shared__ float Xl[64][128];
    const int tid = threadIdx.x;
    const int row0 = blockIdx.x * 64;
    for (int i = tid; i < 64 * 32; i += 256) {
        const int r = i >> 5, c4 = i & 31;
        const int gr = row0 + r;
        float4 v = (gr < n) ? ((const float4*)(Xin + (size_t)gr * 128))[c4]
                            : make_float4(0.f, 0.f, 0.f, 0.f);
        ((float4*)(&Xl[r][0]))[c4] = v;
    }
    __syncthreads();
    const int col4 = tid & 31;   // cols 4*col4 .. +3 (head = col4>>4)
    const int rowg = tid >> 5;   // rows 8*rowg .. +7
    float4 acc[8];
    #pragma unroll
    for (int r = 0; r < 8; ++r) acc[r] = make_float4(0.f, 0.f, 0.f, 0.f);
    const float* Wc = W + col4 * 4;
    for (int kk = 0; kk < 128; kk += 4) {
        const float4 w0 = *(const float4*)(Wc + (size_t)(kk + 0) * 128);
        const float4 w1 = *(const float4*)(Wc + (size_t)(kk + 1) * 128);
        const float4 w2 = *(const float4*)(Wc + (size_t)(kk + 2) * 128);
        const float4 w3 = *(const float4*)(Wc + (size_t)(kk + 3) * 128);
        #pragma unroll
        for (int r = 0; r < 8; ++r) {
            const float4 x = *(const float4*)(&Xl[rowg * 8 + r][kk]);
            acc[r].x = fmaf(x.x, w0.x, acc[r].x); acc[r].y = fmaf(x.x, w0.y, acc[r].y);
            acc[r].z = fmaf(x.x, w0.z, acc[r].z); acc[r].w = fmaf(x.x, w0.w, acc[r].w);
            acc[r].x = fmaf(x.y, w1.x, acc[r].x); acc[r].y = fmaf(x.y, w1.y, acc[r].y);
            acc[r].z = fmaf(x.y, w1.z, acc[r].z); acc[r].w = fmaf(x.y, w1.w, acc[r].w);
            acc[r].x = fmaf(x.z, w2.x, acc[r].x); acc[r].y = fmaf(x.z, w2.y, acc[r].y);
            acc[r].z = fmaf(x.z, w2.z, acc[r].z); acc[r].w = fmaf(x.z, w2.w, acc[r].w);
            acc[r].x = fmaf(x.w, w3.x, acc[r].x); acc[r].y = fmaf(x.w, w3.y, acc[r].y);
            acc[r].z = fmaf(x.w, w3.z, acc[r].z); acc[r].w = fmaf(x.w, w3.w, acc[r].w);
        }
    }
    const float4 av = ((const float4*)avs)[col4];
    const float4 dv = ((const float4*)avd)[col4];
    #pragma unroll
    for (int r = 0; r < 8; ++r) {
        const int grow = row0 + rowg * 8 + r;
        if (grow < n) ((float4*)(S + (size_t)grow * 128))[col4] = acc[r];
        float ps = acc[r].x * av.x + acc[r].y * av.y + acc[r].z * av.z + acc[r].w * av.w;
        float pd = acc[r].x * dv.x + acc[r].y * dv.y + acc[r].z * dv.z + acc[r].w * dv.w;
        #pragma unroll
        for (int off = 8; off; off >>= 1) {  // reduce 16 col-lanes of this head
            ps += __shfl_xor(ps, off);
            pd += __shfl_xor(pd, off);
        }
        if ((col4 & 15) == 0 && grow < n) {
            const int h = col4 >> 4;
            as_[2 * grow + h] = ps;
            ad_[2 * grow + h] = pd;
        }
    }
}

// Fused softmax + gather: one wave per dst; edges of dst d occupy
// [rowp2[d*KC], rowp2[(d+1)*KC]) in ascending src-class order. csr is ushort.
// Fast path (deg<=64): stats in registers, alpha via __shfl. 16-lane edge
// groups: 4 edges concurrent; invalid tail groups skip their loads.
// mode 0=ELU(concat), 1=ReLU(concat), 2=ReLU(head-mean).
__global__ __launch_bounds__(256) void gat_fused(
    const float* __restrict__ S, const float* __restrict__ as_,
    const float* __restrict__ ad_, const int* __restrict__ rowp2,
    const unsigned short* __restrict__ csr, const float* __restrict__ bias,
    float* __restrict__ out, int n, int mode) {
    const int lane = threadIdx.x & 63;
    const int d = (blockIdx.x * blockDim.x + threadIdx.x) >> 6;
    if (d >= n) return;
    const int beg = rowp2[d * KC], end = rowp2[(d + 1) * KC];
    const int deg = end - beg;
    const float2 adv = *(const float2*)(ad_ + 2 * d);
    const int g = lane >> 4;    // edge group 0..3
    const int gl = lane & 15;   // float4 col: gl (head0), 16+gl (head1)
    float4 acc0 = make_float4(0.f, 0.f, 0.f, 0.f);
    float4 acc1 = make_float4(0.f, 0.f, 0.f, 0.f);
    if (deg <= 64) {
        // ---- stats in registers ----
        const bool has = lane < deg;
        const int s_reg = has ? (int)csr[beg + lane] : 0;
        float e0 = -1e30f, e1 = -1e30f;
        if (has) {
            const float2 asv = *(const float2*)(as_ + 2 * s_reg);
            e0 = asv.x + adv.x; e0 = e0 > 0.f ? e0 : 0.2f * e0;
            e1 = asv.y + adv.y; e1 = e1 > 0.f ? e1 : 0.2f * e1;
        }
        float m0 = e0, m1 = e1;
        #pragma unroll
        for (int off = 32; off; off >>= 1) {
            m0 = fmaxf(m0, __shfl_xor(m0, off));
            m1 = fmaxf(m1, __shfl_xor(m1, off));
        }
        const float p0 = has ? __expf(e0 - m0) : 0.f;
        const float p1 = has ? __expf(e1 - m1) : 0.f;
        float s0 = p0, s1 = p1;
        #pragma unroll
        for (int off = 32; off; off >>= 1) {
            s0 += __shfl_xor(s0, off);
            s1 += __shfl_xor(s1, off);
        }
        const float inv0 = 1.f / s0, inv1 = 1.f / s1;
        // ---- gather; alpha via shfl; edges in src-ascending order ----
        int k = 0;
        for (; k + 4 <= deg; k += 4) {
            const int ke = k + g;
            const int sv = __shfl(s_reg, ke);
            const float a0 = __shfl(p0, ke) * inv0;
            const float a1 = __shfl(p1, ke) * inv1;
            const float4* r = (const float4*)(S + ((size_t)sv << 7));
            const float4 v0 = r[gl], v1 = r[16 + gl];
            acc0.x = fmaf(a0, v0.x, acc0.x); acc0.y = fmaf(a0, v0.y, acc0.y);
            acc0.z = fmaf(a0, v0.z, acc0.z); acc0.w = fmaf(a0, v0.w, acc0.w);
            acc1.x = fmaf(a1, v1.x, acc1.x); acc1.y = fmaf(a1, v1.y, acc1.y);
            acc1.z = fmaf(a1, v1.z, acc1.z); acc1.w = fmaf(a1, v1.w, acc1.w);
        }
        if (k < deg) {
            const int ke = k + g;
            const bool valid = ke < deg;
            const int idx = valid ? ke : 0;
            const int sv = __shfl(s_reg, idx);
            const float q0 = __shfl(p0, idx), q1 = __shfl(p1, idx);
            if (valid) {  // invalid groups skip the load entirely
                const float a0 = q0 * inv0, a1 = q1 * inv1;
                const float4* r = (const float4*)(S + ((size_t)sv << 7));
                const float4 v0 = r[gl], v1 = r[16 + gl];
                acc0.x = fmaf(a0, v0.x, acc0.x); acc0.y = fmaf(a0, v0.y, acc0.y);
                acc0.z = fmaf(a0, v0.z, acc0.z); acc0.w = fmaf(a0, v0.w, acc0.w);
                acc1.x = fmaf(a1, v1.x, acc1.x); acc1.y = fmaf(a1, v1.y, acc1.y);
                acc1.z = fmaf(a1, v1.z, acc1.z); acc1.w = fmaf(a1, v1.w, acc1.w);
            }
        }
    } else {
        // ---- slow path (deg>64, rare) ----
        float m0 = -1e30f, m1 = -1e30f;
        for (int i = beg + lane; i < end; i += 64) {
            const int s = (int)csr[i];
            const float2 asv = *(const float2*)(as_ + 2 * s);
            float e0 = asv.x + adv.x; e0 = e0 > 0.f ? e0 : 0.2f * e0;
            float e1 = asv.y + adv.y; e1 = e1 > 0.f ? e1 : 0.2f * e1;
            m0 = fmaxf(m0, e0); m1 = fmaxf(m1, e1);
        }
        #pragma unroll
        for (int off = 32; off; off >>= 1) {
            m0 = fmaxf(m0, __shfl_xor(m0, off));
            m1 = fmaxf(m1, __shfl_xor(m1, off));
        }
        float s0 = 0.f, s1 = 0.f;
        for (int i = beg + lane; i < end; i += 64) {
            const int s = (int)csr[i];
            const float2 asv = *(const float2*)(as_ + 2 * s);
            float e0 = asv.x + adv.x; e0 = e0 > 0.f ? e0 : 0.2f * e0;
            float e1 = asv.y + adv.y; e1 = e1 > 0.f ? e1 : 0.2f * e1;
            s0 += __expf(e0 - m0); s1 += __expf(e1 - m1);
        }
        #pragma unroll
        for (int off = 32; off; off >>= 1) {
            s0 += __shfl_xor(s0, off);
            s1 += __shfl_xor(s1, off);
        }
        const float inv0 = 1.f / s0, inv1 = 1.f / s1;
        for (int k = 0; k < deg; k += 4) {
            const int ke = k + g;
            if (ke < deg) {
                const int sv = (int)csr[beg + ke];
                const float2 asv = *(const float2*)(as_ + 2 * sv);
                float e0 = asv.x + adv.x; e0 = e0 > 0.f ? e0 : 0.2f * e0;
                float e1 = asv.y + adv.y; e1 = e1 > 0.f ? e1 : 0.2f * e1;
                const float a0 = __expf(e0 - m0) * inv0;
                const float a1 = __expf(e1 - m1) * inv1;
                const float4* r = (const float4*)(S + ((size_t)sv << 7));
                const float4 v0 = r[gl], v1 = r[16 + gl];
                acc0.x = fmaf(a0, v0.x, acc0.x); acc0.y = fmaf(a0, v0.y, acc0.y);
                acc0.z = fmaf(a0, v0.z, acc0.z); acc0.w = fmaf(a0, v0.w, acc0.w);
                acc1.x = fmaf(a1, v1.x, acc1.x); acc1.y = fmaf(a1, v1.y, acc1.y);
                acc1.z = fmaf(a1, v1.z, acc1.z); acc1.w = fmaf(a1, v1.w, acc1.w);
            }
        }
    }
    // reduce across the 4 edge groups (lane l, l^16, l^32, l^48 same cols)
    #pragma unroll
    for (int off = 16; off <= 32; off <<= 1) {
        acc0.x += __shfl_xor(acc0.x, off); acc0.y += __shfl_xor(acc0.y, off);
        acc0.z += __shfl_xor(acc0.z, off); acc0.w += __shfl_xor(acc0.w, off);
        acc1.x += __shfl_xor(acc1.x, off); acc1.y += __shfl_xor(acc1.y, off);
        acc1.z += __shfl_xor(acc1.z, off); acc1.w += __shfl_xor(acc1.w, off);
    }
    if (mode == 2) {
        if (lane < 16) {
            const float4 b = ((const float4*)bias)[gl];
            float4 o;
            o.x = fmaxf(0.5f * (acc0.x + acc1.x) + b.x, 0.f);
            o.y = fmaxf(0.5f * (acc0.y + acc1.y) + b.y, 0.f);
            o.z = fmaxf(0.5f * (acc0.z + acc1.z) + b.z, 0.f);
            o.w = fmaxf(0.5f * (acc0.w + acc1.w) + b.w, 0.f);
            ((float4*)(out + (size_t)d * 64))[gl] = o;
        }
    } else if (lane < 32) {
        const int ci = (lane < 16) ? gl : 16 + gl;   // float4 col index
        const float4 a = (lane < 16) ? acc0 : acc1;
        const float4 b = ((const float4*)bias)[ci];
        float4 o;
        o.x = a.x + b.x; o.y = a.y + b.y; o.z = a.z + b.z; o.w = a.w + b.w;
        if (mode == 0) {
            o.x = o.x > 0.f ? o.x : expm1f(o.x);
            o.y = o.y > 0.f ? o.y : expm1f(o.y);
            o.z = o.z > 0.f ? o.z : expm1f(o.z);
            o.w = o.w > 0.f ? o.w : expm1f(o.w);
        } else {
            o.x = fmaxf(o.x, 0.f); o.y = fmaxf(o.y, 0.f);
            o.z = fmaxf(o.z, 0.f); o.w = fmaxf(o.w, 0.f);
        }
        ((float4*)(out + (size_t)d * 128))[ci] = o;
    }
}

extern "C" void kernel_launch(void* const* d_in, const int* in_sizes, int n_in,
                              void* d_out, int out_size, void* d_ws, size_t ws_size,
                              hipStream_t stream) {
    const float* X   = (const float*)d_in[0];
    const void*  EI  = d_in[1];
    const float* W0  = (const float*)d_in[2];
    const float* as0 = (const float*)d_in[3];
    const float* ad0 = (const float*)d_in[4];
    const float* b0  = (const float*)d_in[5];
    const float* W1  = (const float*)d_in[6];
    const float* as1 = (const float*)d_in[7];
    const float* ad1 = (const float*)d_in[8];
    const float* b1  = (const float*)d_in[9];
    const float* W2  = (const float*)d_in[10];
    const float* as2 = (const float*)d_in[11];
    const float* ad2 = (const float*)d_in[12];
    const float* b2  = (const float*)d_in[13];

    const int N  = in_sizes[0] / 128;   // 50000
    const int E  = in_sizes[1] / 2;     // 1600000
    const int ET = E + N;               // + self loops
    const int NBINS = N * KC;           // 650000
    const int NB2 = (NBINS + SCAN_BLOCK - 1) / SCAN_BLOCK;  // 2540
    const int NB3 = (NB2 + SCAN_BLOCK - 1) / SCAN_BLOCK;    // 10

    char* p = (char*)d_ws;
    size_t used = 0;
    auto alloc = [&](size_t bytes) -> void* {
        void* r = p + used;
        used += (bytes + 255) & ~(size_t)255;
        return r;
    };
    float*          S     = (float*)alloc((size_t)N * 128 * 4);
    float*          H0    = (float*)alloc((size_t)N * 128 * 4);
    float*          H1    = (float*)alloc((size_t)N * 128 * 4);
    unsigned short* csr   = (unsigned short*)alloc((size_t)ET * 2);
    int*            rowp2 = (int*)alloc((size_t)(NBINS + 1) * 4);
    int*            cnt2  = (int*)alloc((size_t)NBINS * 4);
    int*            part2 = (int*)alloc((size_t)NBINS * 4);
    int*            bsumA = (int*)alloc((size_t)NB2 * 4);
    int*            partB = (int*)alloc((size_t)NB2 * 4);
    int*            bsumB = (int*)alloc((size_t)NB3 * 4);
    float*          asb   = (float*)alloc((size_t)N * 2 * 4);
    float*          adb   = (float*)alloc((size_t)N * 2 * 4);
    int*            flag  = (int*)alloc(256);
    if (used > ws_size) return;  // fail loudly (validation will catch)
    // epack (6.6MB) + rank (3.3MB) alias S (25.6MB): dead before gemm0.
    const int ETP = (ET + 127) & ~127;
    unsigned*       epack = (unsigned*)S;
    unsigned short* rank  = (unsigned short*)(epack + ETP);

    hipMemsetAsync(cnt2, 0, (size_t)NBINS * 4, stream);
    detect_i64<<<1, 64, 0, stream>>>((const unsigned*)EI, flag);
    gat_convert<<<2048, 256, 0, stream>>>(EI, flag, E, N, epack);
    gat_rankp<<<2048, 256, 0, stream>>>(epack, (long long)ET, N, cnt2, rank);
    scan_stage1<<<NB2, SCAN_BLOCK, 0, stream>>>(cnt2, part2, bsumA, NBINS);
    scan_stage1<<<NB3, SCAN_BLOCK, 0, stream>>>(bsumA, partB, bsumB, NB2);
    scan_stage2<<<1, 64, 0, stream>>>(bsumB, NB3, rowp2, NBINS);
    scan_stage3v2<<<NB2, SCAN_BLOCK, 0, stream>>>(part2, cnt2, bsumA, partB, bsumB, rowp2, NBINS);
    gat_placep<<<2048, 256, 0, stream>>>(epack, rank, rowp2, (long long)ET, N, csr);

    const int gemm_blocks = (N + 63) / 64;
    const int wave_blocks = (N + 3) / 4;  // 4 waves/block, 1 dst/wave

    // layer 0: GATConv(128 -> 64, H=2, concat) + ELU
    gemm_alpha<<<gemm_blocks, 256, 0, stream>>>(X, W0, as0, ad0, S, asb, adb, N);
    gat_fused<<<wave_blocks, 256, 0, stream>>>(S, asb, adb, rowp2, csr, b0, H0, N, 0);
    // layer 1: GATConv(128 -> 64, H=2, concat) + ReLU
    gemm_alpha<<<gemm_blocks, 256, 0, stream>>>(H0, W1, as1, ad1, S, asb, adb, N);
    gat_fused<<<wave_blocks, 256, 0, stream>>>(S, asb, adb, rowp2, csr, b1, H1, N, 1);
    // layer 2: GATConvMean(128 -> 64, H=2, mean) + ReLU
    gemm_alpha<<<gemm_blocks, 256, 0, stream>>>(H1, W2, as2, ad2, S, asb, adb, N);
    gat_fused<<<wave_blocks, 256, 0, stream>>>(S, asb, adb, rowp2, csr, b2, (float*)d_out, N, 2);
}